// Round 5
// baseline (917.786 us; speedup 1.0000x reference)
//
#include <hip/hip_runtime.h>

// ---------------------------------------------------------------------------
// FUSED 2-layer LSTM (Keras gates i,f,g,o) + Dense(27) + softmax. fp32.
// B=32768, T=21, F=126, U=8.
//
// R9: attack the 48% no-issue gap (R8: VALUBusy 52% flat across 2->4
// waves/SIMD, VGPR=52 => compiler built a shallow ds_read->wait->FMA loop;
// LDS latency fully exposed). Changes:
//  1) GEMM hand-pipelined: chunk = 2 q (4 f-rows); issue chunk c+1's
//     ds_reads before chunk c's 32 FMAs via two named fragment structs
//     (static indexing). W-LDS padded with 2 zero rows (f=126,127) and xb
//     with a zeroed tail so both f-halves run a uniform 16 chunks
//     (fh1's dummy q=63 contributes exactly 0).
//  2) x staging via __builtin_amdgcn_global_load_lds size=4: LDS dest is
//     dword-linear in tid (wave-uniform base + lane*4), global source is
//     the strided per-lane address. Kills the VGPR roundtrip + drain
//     ds_writes; __syncthreads at Bb drains vmcnt.
//
// Structure (R7/R8): block=512thr=8 waves, wave=(colgrp x fhalf); f-split
// GEMM partials summed via z1 LDS exchange; role-split recurrence
// (fh0: LSTM1 + h1@W1r + h1@W2k, fh1: LSTM2 + h2@W2r); 2 barriers/t.
// LDS: wlds 16384 + xb 32288 + zb1 16384 + zb2 16384 = 81440 B
//   -> 2 blocks/CU = 16 waves/CU = 4 waves/SIMD. launch_bounds(512,4).
// ---------------------------------------------------------------------------

namespace {
constexpr int T_  = 21;
constexpr int FIN = 126;
constexpr int U_  = 8;
constexpr int NC  = 27;
constexpr int ZC  = 4 * U_;              // 32 gate columns
constexpr int ROW = T_ * FIN;            // 2646 floats per sample
constexpr int NT  = 512;                 // threads per block (8 waves)
constexpr int NXD = 64 * FIN;            // 8064 dwords of x per tile
constexpr int NLD = 16;                  // global_load_lds issues (15 full + 3/4)
}

__device__ __forceinline__ float sigm(float x) {
  return __builtin_amdgcn_rcpf(1.0f + __expf(-x));
}
__device__ __forceinline__ float tanh_f(float x) {
  return 1.0f - 2.0f * __builtin_amdgcn_rcpf(1.0f + __expf(2.0f * x));
}

typedef unsigned int u32;
__device__ __forceinline__ void async_cp4(const float* g, float* l) {
  __builtin_amdgcn_global_load_lds(
      (const __attribute__((address_space(1))) u32*)g,
      (__attribute__((address_space(3))) u32*)l, 4, 0, 0);
}

struct WF { float4 a0, b0, a1, b1, a2, b2, a3, b3; };  // 4 f-rows x 8 cols
struct XF { float2 x01, x23; };                        // 4 f values

__global__ __launch_bounds__(NT, 4) void lstm_fused(
    const float* __restrict__ X,
    const float* __restrict__ W1k, const float* __restrict__ b1,
    const float* __restrict__ W1r,
    const float* __restrict__ W2k, const float* __restrict__ W2r,
    const float* __restrict__ b2,
    const float* __restrict__ Wd, const float* __restrict__ bd,
    float* __restrict__ out)
{
  __shared__ __align__(16) float wlds[128 * ZC];      // 16 KB; rows 126,127 = 0
  __shared__ __align__(16) float xb[NXD + 8];         // 32.3 KB; tail zeroed
  // z exchanges: [col][half][sample]; the 2 partials sit 64 floats apart.
  __shared__ __align__(16) float zb1[ZC * 2 * 64];    // 16 KB
  __shared__ __align__(16) float zb2[ZC * 2 * 64];    // 16 KB

  const int tid = threadIdx.x;
  const int sl  = tid & 63;                                   // sample lane
  const int wv  = __builtin_amdgcn_readfirstlane(tid >> 6);   // 0..7
  const int cg  = wv & 3;        // column group: cols [8cg, 8cg+8)
  const int fh  = wv >> 2;       // f half: 0 -> f in [0,64), 1 -> [64,128)
  const int grp = blockIdx.x;

  // staging source dword offsets (sans t*FIN term): dword d = tid + k*512
  // maps to (s = d/126, f = d%126); source dword = s*ROW + f (+ t*FIN).
  int soff[NLD];
  #pragma unroll
  for (int k = 0; k < NLD; ++k) {
    int d = tid + k * NT;
    int s = d / FIN;
    int f = d - s * FIN;
    soff[k] = s * ROW + f;
  }
  const float* xbase = X + (size_t)grp * 64 * ROW;

  // recurrent weights for this wave's role (fh0: layer1, fh1: layer2)
  const float* Wrr = (fh == 0) ? W1r : W2r;

  // role-overlaid state: fh0 -> (h1,c1), fh1 -> (h2,c2)
  float hs[U_], cs[U_];
  #pragma unroll
  for (int u = 0; u < U_; ++u) { hs[u] = 0.f; cs[u] = 0.f; }

  // prologue: W1k -> wlds (2016 float2 + 32 zero float2), zero xb tail,
  // async-stage x(0), one barrier.
  {
    const float2* w2 = reinterpret_cast<const float2*>(W1k);
    #pragma unroll
    for (int k = 0; k < 4; ++k) {
      int j = tid + k * NT;                 // float2 index over 2048
      float2 v = make_float2(0.f, 0.f);
      if (j < (FIN * ZC) / 2) v = w2[j];
      reinterpret_cast<float2*>(wlds)[j] = v;
    }
    if (tid < 8) xb[NXD + tid] = 0.f;
  }
  #pragma unroll
  for (int k = 0; k < NLD; ++k) {
    if (k < 15 || wv < 6)   // last issue covers dwords 7680..8063 (waves 0..5)
      async_cp4(xbase + soff[k], &xb[k * NT + (wv << 6)]);
  }
  __syncthreads();

  // wave-uniform LDS bases
  const float* wl = &wlds[8 * cg];
  const float* xr = &xb[sl * FIN];
  const int    fb = fh << 6;               // f base: 0 or 64

  for (int t = 0; t < T_; ++t) {
    // ---- layer-1 GEMM partial over this wave's 64 f-rows, pipelined ----
    float4 za, zbv;
    if (fh == 0) {
      za  = reinterpret_cast<const float4*>(b1)[2 * cg];
      zbv = reinterpret_cast<const float4*>(b1)[2 * cg + 1];
    } else {
      za  = make_float4(0.f, 0.f, 0.f, 0.f);
      zbv = make_float4(0.f, 0.f, 0.f, 0.f);
    }

    auto ldw = [&](int c, WF& w) {
      const float* p = wl + (fb + 4 * c) * ZC;
      w.a0 = *reinterpret_cast<const float4*>(p);
      w.b0 = *reinterpret_cast<const float4*>(p + 4);
      w.a1 = *reinterpret_cast<const float4*>(p + ZC);
      w.b1 = *reinterpret_cast<const float4*>(p + ZC + 4);
      w.a2 = *reinterpret_cast<const float4*>(p + 2 * ZC);
      w.b2 = *reinterpret_cast<const float4*>(p + 2 * ZC + 4);
      w.a3 = *reinterpret_cast<const float4*>(p + 3 * ZC);
      w.b3 = *reinterpret_cast<const float4*>(p + 3 * ZC + 4);
    };
    auto ldx = [&](int c, XF& x) {
      const float* p = xr + fb + 4 * c;
      x.x01 = *reinterpret_cast<const float2*>(p);
      x.x23 = *reinterpret_cast<const float2*>(p + 2);
    };
    auto dofma = [&](const WF& w, const XF& x) {
      za.x  = fmaf(x.x01.x, w.a0.x, za.x);  za.y  = fmaf(x.x01.x, w.a0.y, za.y);
      za.z  = fmaf(x.x01.x, w.a0.z, za.z);  za.w  = fmaf(x.x01.x, w.a0.w, za.w);
      zbv.x = fmaf(x.x01.x, w.b0.x, zbv.x); zbv.y = fmaf(x.x01.x, w.b0.y, zbv.y);
      zbv.z = fmaf(x.x01.x, w.b0.z, zbv.z); zbv.w = fmaf(x.x01.x, w.b0.w, zbv.w);
      za.x  = fmaf(x.x01.y, w.a1.x, za.x);  za.y  = fmaf(x.x01.y, w.a1.y, za.y);
      za.z  = fmaf(x.x01.y, w.a1.z, za.z);  za.w  = fmaf(x.x01.y, w.a1.w, za.w);
      zbv.x = fmaf(x.x01.y, w.b1.x, zbv.x); zbv.y = fmaf(x.x01.y, w.b1.y, zbv.y);
      zbv.z = fmaf(x.x01.y, w.b1.z, zbv.z); zbv.w = fmaf(x.x01.y, w.b1.w, zbv.w);
      za.x  = fmaf(x.x23.x, w.a2.x, za.x);  za.y  = fmaf(x.x23.x, w.a2.y, za.y);
      za.z  = fmaf(x.x23.x, w.a2.z, za.z);  za.w  = fmaf(x.x23.x, w.a2.w, za.w);
      zbv.x = fmaf(x.x23.x, w.b2.x, zbv.x); zbv.y = fmaf(x.x23.x, w.b2.y, zbv.y);
      zbv.z = fmaf(x.x23.x, w.b2.z, zbv.z); zbv.w = fmaf(x.x23.x, w.b2.w, zbv.w);
      za.x  = fmaf(x.x23.y, w.a3.x, za.x);  za.y  = fmaf(x.x23.y, w.a3.y, za.y);
      za.z  = fmaf(x.x23.y, w.a3.z, za.z);  za.w  = fmaf(x.x23.y, w.a3.w, za.w);
      zbv.x = fmaf(x.x23.y, w.b3.x, zbv.x); zbv.y = fmaf(x.x23.y, w.b3.y, zbv.y);
      zbv.z = fmaf(x.x23.y, w.b3.z, zbv.z); zbv.w = fmaf(x.x23.y, w.b3.w, zbv.w);
    };

    {
      WF wA, wB; XF xA, xB;
      ldw(0, wA); ldx(0, xA);
      #pragma unroll
      for (int cc = 0; cc < 8; ++cc) {
        ldw(2 * cc + 1, wB); ldx(2 * cc + 1, xB);
        dofma(wA, xA);
        if (cc < 7) { ldw(2 * cc + 2, wA); ldx(2 * cc + 2, xA); }
        dofma(wB, xB);
      }
    }

    // fh0 adds the layer-1 recurrent term h1(t-1) @ W1r
    if (fh == 0) {
      #pragma unroll
      for (int k = 0; k < U_; ++k) {
        float hv = hs[k];
        const float4* w = reinterpret_cast<const float4*>(&Wrr[k * ZC + 8 * cg]);
        float4 w0 = w[0], w1 = w[1];
        za.x  = fmaf(hv, w0.x, za.x);  za.y  = fmaf(hv, w0.y, za.y);
        za.z  = fmaf(hv, w0.z, za.z);  za.w  = fmaf(hv, w0.w, za.w);
        zbv.x = fmaf(hv, w1.x, zbv.x); zbv.y = fmaf(hv, w1.y, zbv.y);
        zbv.z = fmaf(hv, w1.z, zbv.z); zbv.w = fmaf(hv, w1.w, zbv.w);
      }
    }

    // write z1 partial: zb1[(col)*128 + fh*64 + sl]
    {
      float* zp = &zb1[(8 * cg) * 128 + fh * 64 + sl];
      zp[0 * 128] = za.x;  zp[1 * 128] = za.y;  zp[2 * 128] = za.z;  zp[3 * 128] = za.w;
      zp[4 * 128] = zbv.x; zp[5 * 128] = zbv.y; zp[6 * 128] = zbv.z; zp[7 * 128] = zbv.w;
    }
    __syncthreads();                                   // Ba: z1 visible, x reads done

    // async-stage x(t+1) straight into LDS (lands before Bb's vmcnt drain)
    if (t + 1 < T_) {
      const float* xt = xbase + (size_t)(t + 1) * FIN;
      #pragma unroll
      for (int k = 0; k < NLD; ++k) {
        if (k < 15 || wv < 6)
          async_cp4(xt + soff[k], &xb[k * NT + (wv << 6)]);
      }
    }

    if (fh == 0) {
      // ---- LSTM1 update (fh0 waves; z1 = sum of 2 partials) ----
      #pragma unroll
      for (int u = 0; u < U_; ++u) {
        const float* p0 = &zb1[u * 128 + sl];
        float zi = p0[0]        + p0[64];
        float zf = p0[ 8 * 128] + p0[ 8 * 128 + 64];
        float zg = p0[16 * 128] + p0[16 * 128 + 64];
        float zo = p0[24 * 128] + p0[24 * 128 + 64];
        float iv = sigm(zi), fv = sigm(zf), gv = tanh_f(zg), ov = sigm(zo);
        float cn = fv * cs[u] + iv * gv;
        cs[u] = cn;
        hs[u] = ov * tanh_f(cn);
      }
      // z2 feed-forward partial: b2 + h1 @ W2k (this wave's 8 cols)
      float4 za2 = reinterpret_cast<const float4*>(b2)[2 * cg];
      float4 zb2v = reinterpret_cast<const float4*>(b2)[2 * cg + 1];
      #pragma unroll
      for (int k = 0; k < U_; ++k) {
        float hv = hs[k];
        const float4* w = reinterpret_cast<const float4*>(&W2k[k * ZC + 8 * cg]);
        float4 w0 = w[0], w1 = w[1];
        za2.x  = fmaf(hv, w0.x, za2.x);  za2.y  = fmaf(hv, w0.y, za2.y);
        za2.z  = fmaf(hv, w0.z, za2.z);  za2.w  = fmaf(hv, w0.w, za2.w);
        zb2v.x = fmaf(hv, w1.x, zb2v.x); zb2v.y = fmaf(hv, w1.y, zb2v.y);
        zb2v.z = fmaf(hv, w1.z, zb2v.z); zb2v.w = fmaf(hv, w1.w, zb2v.w);
      }
      float* zp = &zb2[(8 * cg) * 128 + 0 * 64 + sl];
      zp[0 * 128] = za2.x;  zp[1 * 128] = za2.y;  zp[2 * 128] = za2.z;  zp[3 * 128] = za2.w;
      zp[4 * 128] = zb2v.x; zp[5 * 128] = zb2v.y; zp[6 * 128] = zb2v.z; zp[7 * 128] = zb2v.w;
    } else {
      // z2 recurrent partial: h2(t-1) @ W2r (this wave's 8 cols)
      float4 za2  = make_float4(0.f, 0.f, 0.f, 0.f);
      float4 zb2v = make_float4(0.f, 0.f, 0.f, 0.f);
      #pragma unroll
      for (int k = 0; k < U_; ++k) {
        float hv = hs[k];
        const float4* w = reinterpret_cast<const float4*>(&Wrr[k * ZC + 8 * cg]);
        float4 w0 = w[0], w1 = w[1];
        za2.x  = fmaf(hv, w0.x, za2.x);  za2.y  = fmaf(hv, w0.y, za2.y);
        za2.z  = fmaf(hv, w0.z, za2.z);  za2.w  = fmaf(hv, w0.w, za2.w);
        zb2v.x = fmaf(hv, w1.x, zb2v.x); zb2v.y = fmaf(hv, w1.y, zb2v.y);
        zb2v.z = fmaf(hv, w1.z, zb2v.z); zb2v.w = fmaf(hv, w1.w, zb2v.w);
      }
      float* zp = &zb2[(8 * cg) * 128 + 1 * 64 + sl];
      zp[0 * 128] = za2.x;  zp[1 * 128] = za2.y;  zp[2 * 128] = za2.z;  zp[3 * 128] = za2.w;
      zp[4 * 128] = zb2v.x; zp[5 * 128] = zb2v.y; zp[6 * 128] = zb2v.z; zp[7 * 128] = zb2v.w;
    }
    __syncthreads();                                   // Bb: z2 + x(t+1) visible

    if (fh == 1) {
      // ---- LSTM2 update (fh1 waves; z2 = sum of 2 partials) ----
      #pragma unroll
      for (int u = 0; u < U_; ++u) {
        const float* p0 = &zb2[u * 128 + sl];
        float zi = p0[0]        + p0[64];
        float zf = p0[ 8 * 128] + p0[ 8 * 128 + 64];
        float zg = p0[16 * 128] + p0[16 * 128 + 64];
        float zo = p0[24 * 128] + p0[24 * 128 + 64];
        float iv = sigm(zi), fv = sigm(zf), gv = tanh_f(zg), ov = sigm(zo);
        float cn = fv * cs[u] + iv * gv;
        cs[u] = cn;
        hs[u] = ov * tanh_f(cn);
      }
    }
  }

  // ---- Dense(27) + softmax: fh1 waves hold h2(T-1); wave 4 stages ----
  if (wv == 4) {
    float lg[NC];
    float m = -1e30f;
    #pragma unroll
    for (int c = 0; c < NC; ++c) {
      float acc = bd[c];
      #pragma unroll
      for (int k = 0; k < U_; ++k) acc = fmaf(hs[k], Wd[k * NC + c], acc);
      lg[c] = acc;
      m = fmaxf(m, acc);
    }
    float ssum = 0.f;
    #pragma unroll
    for (int c = 0; c < NC; ++c) {
      float e = __expf(lg[c] - m);
      lg[c] = e;
      ssum += e;
    }
    float inv = 1.0f / ssum;
    #pragma unroll
    for (int c = 0; c < NC; ++c) zb1[sl * NC + c] = lg[c] * inv;
  }
  __syncthreads();
  {
    float* oblk = out + (size_t)grp * 64 * NC;
    #pragma unroll
    for (int k = 0; k < 4; ++k) {
      int j = tid + k * NT;
      if (j < 64 * NC) oblk[j] = zb1[j];   // coalesced store
    }
  }
}

extern "C" void kernel_launch(void* const* d_in, const int* in_sizes, int n_in,
                              void* d_out, int out_size, void* d_ws, size_t ws_size,
                              hipStream_t stream) {
  const float* X   = (const float*)d_in[0];
  const float* W1k = (const float*)d_in[1];
  const float* W1r = (const float*)d_in[2];
  const float* b1  = (const float*)d_in[3];
  const float* W2k = (const float*)d_in[4];
  const float* W2r = (const float*)d_in[5];
  const float* b2  = (const float*)d_in[6];
  const float* Wd  = (const float*)d_in[7];
  const float* bd  = (const float*)d_in[8];
  float* out = (float*)d_out;
  (void)d_ws; (void)ws_size;   // workspace intentionally unused (fused design)

  const int B    = in_sizes[0] / ROW;   // 32768
  const int ngrp = B / 64;              // 512

  lstm_fused<<<dim3(ngrp), NT, 0, stream>>>(
      X, W1k, b1, W1r, W2k, W2r, b2, Wd, bd, out);
}

// Round 6
// 515.417 us; speedup vs baseline: 1.7807x; 1.7807x over previous
//
#include <hip/hip_runtime.h>

// ---------------------------------------------------------------------------
// FUSED 2-layer LSTM (Keras gates i,f,g,o) + Dense(27) + softmax. fp32.
// B=32768, T=21, F=126, U=8.
//
// R10: W1k through the SCALAR pipe. R6/R8 both stalled at ~220us, 52%
// VALUBusy: per-wave W-broadcast re-reads (252 vmem or 160 LDS insts per
// wave per t = ~2560 shared-pipe ops/t/CU) oversubscribe L1/LDS ~2.5x vs
// the 512 real FMAs. W is wave-uniform -> s_load_dwordx8 into SGPRs
// (inline asm; compiler wouldn't scalarize). 8-row groups: 8 s_load +
// 4 ds_read_b64 (x) + lgkmcnt(0) drain (SMEM retires out-of-order ->
// counted waits unsafe; drain is covered by 4-wave/SIMD TLP) + 64 FMA
// with SGPR src. LDS W buffer deleted. R9's global_load_lds + deep VGPR
// pipeline reverted (853MB fetch / 744MB write scratch-thrash anomaly).
//
// Structure (R8): block=512thr=8 waves, wave=(colgrp x fhalf); f-split
// GEMM partials summed via z1 LDS exchange; role-split recurrence
// (fh0: LSTM1 + h1@W1r + h1@W2k, fh1: LSTM2 + h2@W2r); 2 barriers/t;
// single x buffer, reg-prefetch of x(t+1) drained in the Ba..Bb window.
// LDS: xb 32256 + zb1 16384 + zb2 16384 = 65024 B -> 2 blocks/CU
//   = 16 waves/CU = 4 waves/SIMD. launch_bounds(512,4) caps VGPR 128.
// ---------------------------------------------------------------------------

namespace {
constexpr int T_  = 21;
constexpr int FIN = 126;
constexpr int U_  = 8;
constexpr int NC  = 27;
constexpr int ZC  = 4 * U_;              // 32 gate columns
constexpr int ROW = T_ * FIN;            // 2646 floats per sample
constexpr int NT  = 512;                 // threads per block (8 waves)
constexpr int NPF = 8;                   // float2 staged per thread
}

__device__ __forceinline__ float sigm(float x) {
  return __builtin_amdgcn_rcpf(1.0f + __expf(-x));
}
__device__ __forceinline__ float tanh_f(float x) {
  return 1.0f - 2.0f * __builtin_amdgcn_rcpf(1.0f + __expf(2.0f * x));
}

typedef __attribute__((ext_vector_type(8))) float f32x8;

struct SW8 { f32x8 r0, r1, r2, r3, r4, r5, r6, r7; };
struct SW6 { f32x8 r0, r1, r2, r3, r4, r5; };

// 8 wave-uniform rows of W (8 floats each) -> SGPRs. Offsets are
// compile-time immediates; base is an SGPR pair (uniform pointer).
template<int G>
__device__ __forceinline__ void sload8(SW8& A, const float* wkp) {
  asm volatile(
      "s_load_dwordx8 %0, %8, %9\n\t"
      "s_load_dwordx8 %1, %8, %10\n\t"
      "s_load_dwordx8 %2, %8, %11\n\t"
      "s_load_dwordx8 %3, %8, %12\n\t"
      "s_load_dwordx8 %4, %8, %13\n\t"
      "s_load_dwordx8 %5, %8, %14\n\t"
      "s_load_dwordx8 %6, %8, %15\n\t"
      "s_load_dwordx8 %7, %8, %16"
      : "=s"(A.r0), "=s"(A.r1), "=s"(A.r2), "=s"(A.r3),
        "=s"(A.r4), "=s"(A.r5), "=s"(A.r6), "=s"(A.r7)
      : "s"(wkp),
        "i"(G * 1024 + 0),   "i"(G * 1024 + 128),
        "i"(G * 1024 + 256), "i"(G * 1024 + 384),
        "i"(G * 1024 + 512), "i"(G * 1024 + 640),
        "i"(G * 1024 + 768), "i"(G * 1024 + 896));
}

// 6-row tail (fh1: f = 120..125), rows 56..61 relative to the half base.
__device__ __forceinline__ void sload6(SW6& A, const float* wkp) {
  asm volatile(
      "s_load_dwordx8 %0, %6, %7\n\t"
      "s_load_dwordx8 %1, %6, %8\n\t"
      "s_load_dwordx8 %2, %6, %9\n\t"
      "s_load_dwordx8 %3, %6, %10\n\t"
      "s_load_dwordx8 %4, %6, %11\n\t"
      "s_load_dwordx8 %5, %6, %12"
      : "=s"(A.r0), "=s"(A.r1), "=s"(A.r2), "=s"(A.r3),
        "=s"(A.r4), "=s"(A.r5)
      : "s"(wkp),
        "i"(56 * 128), "i"(57 * 128), "i"(58 * 128),
        "i"(59 * 128), "i"(60 * 128), "i"(61 * 128));
}

// Drain: ties the s_load results AND the x ds_read results through the
// asm so nothing consuming them can be hoisted above the waitcnt
// (rule #18: a bare waitcnt asm does not order register-only FMAs).
__device__ __forceinline__ void swait8(SW8& A, float2& x0, float2& x1,
                                       float2& x2, float2& x3) {
  asm volatile("s_waitcnt lgkmcnt(0)"
               : "+s"(A.r0), "+s"(A.r1), "+s"(A.r2), "+s"(A.r3),
                 "+s"(A.r4), "+s"(A.r5), "+s"(A.r6), "+s"(A.r7),
                 "+v"(x0), "+v"(x1), "+v"(x2), "+v"(x3));
}
__device__ __forceinline__ void swait6(SW6& A, float2& x0, float2& x1,
                                       float2& x2) {
  asm volatile("s_waitcnt lgkmcnt(0)"
               : "+s"(A.r0), "+s"(A.r1), "+s"(A.r2), "+s"(A.r3),
                 "+s"(A.r4), "+s"(A.r5),
                 "+v"(x0), "+v"(x1), "+v"(x2));
}

__device__ __forceinline__ void fma_row(float* acc, float xv, const f32x8& w) {
  #pragma unroll
  for (int c = 0; c < 8; ++c) acc[c] = fmaf(xv, w[c], acc[c]);
}

// GEMM over this wave's f-half: NG full 8-row groups (+ optional 6-row tail).
template<int NG, int TROWS, int G = 0>
__device__ __forceinline__ void gemm_groups(const float* wkp, const float* xh,
                                            float* acc) {
  if constexpr (G < NG) {
    SW8 A;
    sload8<G>(A, wkp);
    float2 x0 = *reinterpret_cast<const float2*>(xh + 8 * G + 0);
    float2 x1 = *reinterpret_cast<const float2*>(xh + 8 * G + 2);
    float2 x2 = *reinterpret_cast<const float2*>(xh + 8 * G + 4);
    float2 x3 = *reinterpret_cast<const float2*>(xh + 8 * G + 6);
    swait8(A, x0, x1, x2, x3);
    fma_row(acc, x0.x, A.r0); fma_row(acc, x0.y, A.r1);
    fma_row(acc, x1.x, A.r2); fma_row(acc, x1.y, A.r3);
    fma_row(acc, x2.x, A.r4); fma_row(acc, x2.y, A.r5);
    fma_row(acc, x3.x, A.r6); fma_row(acc, x3.y, A.r7);
    gemm_groups<NG, TROWS, G + 1>(wkp, xh, acc);
  } else if constexpr (TROWS == 6) {
    SW6 A;
    sload6(A, wkp);
    float2 x0 = *reinterpret_cast<const float2*>(xh + 8 * G + 0);
    float2 x1 = *reinterpret_cast<const float2*>(xh + 8 * G + 2);
    float2 x2 = *reinterpret_cast<const float2*>(xh + 8 * G + 4);
    swait6(A, x0, x1, x2);
    fma_row(acc, x0.x, A.r0); fma_row(acc, x0.y, A.r1);
    fma_row(acc, x1.x, A.r2); fma_row(acc, x1.y, A.r3);
    fma_row(acc, x2.x, A.r4); fma_row(acc, x2.y, A.r5);
  }
}

__global__ __launch_bounds__(NT, 4) void lstm_fused(
    const float* __restrict__ X,
    const float* __restrict__ W1k, const float* __restrict__ b1,
    const float* __restrict__ W1r,
    const float* __restrict__ W2k, const float* __restrict__ W2r,
    const float* __restrict__ b2,
    const float* __restrict__ Wd, const float* __restrict__ bd,
    float* __restrict__ out)
{
  __shared__ __align__(16) float xb[64 * FIN];        // 32256 B, single buffer
  // z exchanges: [col][half][sample]; the 2 partials sit 64 floats apart.
  __shared__ __align__(16) float zb1[ZC * 2 * 64];    // 16384 B
  __shared__ __align__(16) float zb2[ZC * 2 * 64];    // 16384 B

  const int tid = threadIdx.x;
  const int sl  = tid & 63;                                   // sample lane
  const int wv  = __builtin_amdgcn_readfirstlane(tid >> 6);   // 0..7
  const int cg  = wv & 3;        // column group: cols [8cg, 8cg+8)
  const int fh  = wv >> 2;       // f half: 0 -> f in [0,64), 1 -> [64,126)
  const int grp = blockIdx.x;

  // staging decomposition: j over 64*63 float2 elems, 8 per thread
  int  goff[NPF];
  int  loff[NPF];
  bool val[NPF];
  #pragma unroll
  for (int k = 0; k < NPF; ++k) {
    int j = tid + k * NT;
    val[k] = (j < 64 * 63);
    int s = j / 63;
    int q = j - s * 63;
    goff[k] = s * ROW + 2 * q;
    loff[k] = s * FIN + 2 * q;
  }

  const float* xbase = X + (size_t)grp * 64 * ROW;

  // wave-uniform W base for the scalar loads: row f, cols [8cg, 8cg+8)
  const float* wkp = W1k + (fh ? 64 * ZC : 0) + 8 * cg;
  // recurrent weights for this wave's role (fh0: layer1, fh1: layer2)
  const float* Wrr = (fh == 0) ? W1r : W2r;

  // role-overlaid state: fh0 -> (h1,c1), fh1 -> (h2,c2)
  float hs[U_], cs[U_];
  #pragma unroll
  for (int u = 0; u < U_; ++u) { hs[u] = 0.f; cs[u] = 0.f; }

  // prologue: x(0) -> regs -> LDS; prefetch x(1); barrier
  float2 pf[NPF];
  #pragma unroll
  for (int k = 0; k < NPF; ++k)
    if (val[k]) pf[k] = *reinterpret_cast<const float2*>(xbase + goff[k]);
  #pragma unroll
  for (int k = 0; k < NPF; ++k)
    if (val[k]) *reinterpret_cast<float2*>(&xb[loff[k]]) = pf[k];
  {
    const float* xt = xbase + FIN;
    #pragma unroll
    for (int k = 0; k < NPF; ++k)
      if (val[k]) pf[k] = *reinterpret_cast<const float2*>(xt + goff[k]);
  }
  __syncthreads();

  const float* xr = &xb[sl * FIN];

  for (int t = 0; t < T_; ++t) {
    // ---- layer-1 GEMM partial over this wave's f-half (W via SGPRs) ----
    float acc[8];
    if (fh == 0) {
      float4 ba = reinterpret_cast<const float4*>(b1)[2 * cg];
      float4 bb = reinterpret_cast<const float4*>(b1)[2 * cg + 1];
      acc[0] = ba.x; acc[1] = ba.y; acc[2] = ba.z; acc[3] = ba.w;
      acc[4] = bb.x; acc[5] = bb.y; acc[6] = bb.z; acc[7] = bb.w;
    } else {
      #pragma unroll
      for (int c = 0; c < 8; ++c) acc[c] = 0.f;
    }

    if (fh == 0) gemm_groups<8, 0>(wkp, xr, acc);        // f 0..63
    else         gemm_groups<7, 6>(wkp, xr + 64, acc);   // f 64..125

    // fh0 adds the layer-1 recurrent term h1(t-1) @ W1r
    if (fh == 0) {
      #pragma unroll
      for (int k = 0; k < U_; ++k) {
        float hv = hs[k];
        const float4* w = reinterpret_cast<const float4*>(&Wrr[k * ZC + 8 * cg]);
        float4 w0 = w[0], w1 = w[1];
        acc[0] = fmaf(hv, w0.x, acc[0]); acc[1] = fmaf(hv, w0.y, acc[1]);
        acc[2] = fmaf(hv, w0.z, acc[2]); acc[3] = fmaf(hv, w0.w, acc[3]);
        acc[4] = fmaf(hv, w1.x, acc[4]); acc[5] = fmaf(hv, w1.y, acc[5]);
        acc[6] = fmaf(hv, w1.z, acc[6]); acc[7] = fmaf(hv, w1.w, acc[7]);
      }
    }

    // write z1 partial: zb1[(col)*128 + fh*64 + sl]
    {
      float* zp = &zb1[(8 * cg) * 128 + fh * 64 + sl];
      #pragma unroll
      for (int c = 0; c < 8; ++c) zp[c * 128] = acc[c];
    }
    __syncthreads();                                   // Ba: z1 visible, x reads done

    // drain x(t+1) into LDS (window Ba..Bb), issue prefetch of x(t+2)
    if (t + 1 < T_) {
      #pragma unroll
      for (int k = 0; k < NPF; ++k)
        if (val[k]) *reinterpret_cast<float2*>(&xb[loff[k]]) = pf[k];
    }
    if (t + 2 < T_) {
      const float* xt = xbase + (size_t)(t + 2) * FIN;
      #pragma unroll
      for (int k = 0; k < NPF; ++k)
        if (val[k]) pf[k] = *reinterpret_cast<const float2*>(xt + goff[k]);
    }

    if (fh == 0) {
      // ---- LSTM1 update (fh0 waves; z1 = sum of 2 partials) ----
      #pragma unroll
      for (int u = 0; u < U_; ++u) {
        const float* p0 = &zb1[u * 128 + sl];
        float zi = p0[0]        + p0[64];
        float zf = p0[ 8 * 128] + p0[ 8 * 128 + 64];
        float zg = p0[16 * 128] + p0[16 * 128 + 64];
        float zo = p0[24 * 128] + p0[24 * 128 + 64];
        float iv = sigm(zi), fv = sigm(zf), gv = tanh_f(zg), ov = sigm(zo);
        float cn = fv * cs[u] + iv * gv;
        cs[u] = cn;
        hs[u] = ov * tanh_f(cn);
      }
      // z2 feed-forward partial: b2 + h1 @ W2k (this wave's 8 cols)
      float4 za2  = reinterpret_cast<const float4*>(b2)[2 * cg];
      float4 zb2v = reinterpret_cast<const float4*>(b2)[2 * cg + 1];
      #pragma unroll
      for (int k = 0; k < U_; ++k) {
        float hv = hs[k];
        const float4* w = reinterpret_cast<const float4*>(&W2k[k * ZC + 8 * cg]);
        float4 w0 = w[0], w1 = w[1];
        za2.x  = fmaf(hv, w0.x, za2.x);  za2.y  = fmaf(hv, w0.y, za2.y);
        za2.z  = fmaf(hv, w0.z, za2.z);  za2.w  = fmaf(hv, w0.w, za2.w);
        zb2v.x = fmaf(hv, w1.x, zb2v.x); zb2v.y = fmaf(hv, w1.y, zb2v.y);
        zb2v.z = fmaf(hv, w1.z, zb2v.z); zb2v.w = fmaf(hv, w1.w, zb2v.w);
      }
      float* zp = &zb2[(8 * cg) * 128 + 0 * 64 + sl];
      zp[0 * 128] = za2.x;  zp[1 * 128] = za2.y;  zp[2 * 128] = za2.z;  zp[3 * 128] = za2.w;
      zp[4 * 128] = zb2v.x; zp[5 * 128] = zb2v.y; zp[6 * 128] = zb2v.z; zp[7 * 128] = zb2v.w;
    } else {
      // z2 recurrent partial: h2(t-1) @ W2r (this wave's 8 cols)
      float4 za2  = make_float4(0.f, 0.f, 0.f, 0.f);
      float4 zb2v = make_float4(0.f, 0.f, 0.f, 0.f);
      #pragma unroll
      for (int k = 0; k < U_; ++k) {
        float hv = hs[k];
        const float4* w = reinterpret_cast<const float4*>(&Wrr[k * ZC + 8 * cg]);
        float4 w0 = w[0], w1 = w[1];
        za2.x  = fmaf(hv, w0.x, za2.x);  za2.y  = fmaf(hv, w0.y, za2.y);
        za2.z  = fmaf(hv, w0.z, za2.z);  za2.w  = fmaf(hv, w0.w, za2.w);
        zb2v.x = fmaf(hv, w1.x, zb2v.x); zb2v.y = fmaf(hv, w1.y, zb2v.y);
        zb2v.z = fmaf(hv, w1.z, zb2v.z); zb2v.w = fmaf(hv, w1.w, zb2v.w);
      }
      float* zp = &zb2[(8 * cg) * 128 + 1 * 64 + sl];
      zp[0 * 128] = za2.x;  zp[1 * 128] = za2.y;  zp[2 * 128] = za2.z;  zp[3 * 128] = za2.w;
      zp[4 * 128] = zb2v.x; zp[5 * 128] = zb2v.y; zp[6 * 128] = zb2v.z; zp[7 * 128] = zb2v.w;
    }
    __syncthreads();                                   // Bb: z2 + x(t+1) visible

    if (fh == 1) {
      // ---- LSTM2 update (fh1 waves; z2 = sum of 2 partials) ----
      #pragma unroll
      for (int u = 0; u < U_; ++u) {
        const float* p0 = &zb2[u * 128 + sl];
        float zi = p0[0]        + p0[64];
        float zf = p0[ 8 * 128] + p0[ 8 * 128 + 64];
        float zg = p0[16 * 128] + p0[16 * 128 + 64];
        float zo = p0[24 * 128] + p0[24 * 128 + 64];
        float iv = sigm(zi), fv = sigm(zf), gv = tanh_f(zg), ov = sigm(zo);
        float cn = fv * cs[u] + iv * gv;
        cs[u] = cn;
        hs[u] = ov * tanh_f(cn);
      }
    }
  }

  // ---- Dense(27) + softmax: fh1 waves hold h2(T-1); wave 4 stages ----
  if (wv == 4) {
    float lg[NC];
    float m = -1e30f;
    #pragma unroll
    for (int c = 0; c < NC; ++c) {
      float acc = bd[c];
      #pragma unroll
      for (int k = 0; k < U_; ++k) acc = fmaf(hs[k], Wd[k * NC + c], acc);
      lg[c] = acc;
      m = fmaxf(m, acc);
    }
    float ssum = 0.f;
    #pragma unroll
    for (int c = 0; c < NC; ++c) {
      float e = __expf(lg[c] - m);
      lg[c] = e;
      ssum += e;
    }
    float inv = 1.0f / ssum;
    #pragma unroll
    for (int c = 0; c < NC; ++c) zb1[sl * NC + c] = lg[c] * inv;
  }
  __syncthreads();
  {
    float* oblk = out + (size_t)grp * 64 * NC;
    #pragma unroll
    for (int k = 0; k < 4; ++k) {
      int j = tid + k * NT;
      if (j < 64 * NC) oblk[j] = zb1[j];   // coalesced store
    }
  }
}

extern "C" void kernel_launch(void* const* d_in, const int* in_sizes, int n_in,
                              void* d_out, int out_size, void* d_ws, size_t ws_size,
                              hipStream_t stream) {
  const float* X   = (const float*)d_in[0];
  const float* W1k = (const float*)d_in[1];
  const float* W1r = (const float*)d_in[2];
  const float* b1  = (const float*)d_in[3];
  const float* W2k = (const float*)d_in[4];
  const float* W2r = (const float*)d_in[5];
  const float* b2  = (const float*)d_in[6];
  const float* Wd  = (const float*)d_in[7];
  const float* bd  = (const float*)d_in[8];
  float* out = (float*)d_out;
  (void)d_ws; (void)ws_size;   // workspace intentionally unused (fused design)

  const int B    = in_sizes[0] / ROW;   // 32768
  const int ngrp = B / 64;              // 512

  lstm_fused<<<dim3(ngrp), NT, 0, stream>>>(
      X, W1k, b1, W1r, W2k, W2r, b2, Wd, bd, out);
}